// Round 10
// baseline (590.281 us; speedup 1.0000x reference)
//
#include <hip/hip_runtime.h>
#include <stdint.h>

#define NN 50000
#define NE 800000
#define HID 128
#define NG 64
#define BN_EPS 1e-5f
#define SCAN_BLOCKS 196  // 196*256 = 50176 >= NN
#define GEMM_BLOCKS ((NN + 127) / 128)
#define SC_NB 8                                  // buckets (== XCD count)
#define SC_BSZ ((NN + SC_NB - 1) / SC_NB)        // 6250 nodes per bucket
#define SC_CHUNK 4096                            // edges per block
#define SC_CHUNKS ((NE + SC_CHUNK - 1) / SC_CHUNK)
#define AGG_PASSES 4                             // h cache-blocking: 12.5k rows = 3.2MB/XCD-L2

typedef __bf16 bf16x8 __attribute__((ext_vector_type(8)));
typedef float floatx4 __attribute__((ext_vector_type(4)));

__device__ __forceinline__ float b2f(unsigned short u) {
    union { unsigned int i; float f; } x; x.i = ((unsigned int)u) << 16; return x.f;
}
__device__ __forceinline__ float blo(unsigned int d) { return __uint_as_float(d << 16); }
__device__ __forceinline__ float bhi(unsigned int d) { return __uint_as_float(d & 0xffff0000u); }
__device__ __forceinline__ unsigned short f2b(float f) {
    union { float f; unsigned int i; } x; x.f = f; unsigned int i = x.i;
    if ((i & 0x7f800000u) == 0x7f800000u) return (unsigned short)(i >> 16); // inf/nan
    return (unsigned short)((i + 0x7fffu + ((i >> 16) & 1u)) >> 16);        // RNE
}
__device__ __forceinline__ unsigned int pack2(float f0, float f1) {
    return (((unsigned int)f2b(f1)) << 16) | f2b(f0);
}
// folded BN scale/shift for column c (from raw sums)
__device__ __forceinline__ float2 bn_pair(const float* __restrict__ bnstat,
                                          const float* __restrict__ gamma,
                                          const float* __restrict__ beta, int c) {
    float mu = bnstat[c] * (1.f / NN);
    float var = bnstat[128 + c] * (1.f / NN) - mu * mu;
    float s = gamma[c] * rsqrtf(var + BN_EPS);
    return make_float2(s, beta[c] - mu * s);
}

// ---------------- setup (incl. weight prep) ----------------
// Pre-transpose fp32 [Wl;Wr] (256x128) into bf16 MFMA B-fragment order:
// Bp[layer][nt][kk][lane][j] = Wcat[kk*32+(lane>>4)*8+j][nt*16+(lane&15)]
__global__ void k_setup(const float* __restrict__ x, unsigned short* xb, int* deg,
                        int* gstart, int* gend, float* bnstats,
                        float* pool_sum, int* pool_max,
                        const float* __restrict__ Wl0, const float* __restrict__ Wr0,
                        const float* __restrict__ Wl1, const float* __restrict__ Wr1,
                        const float* __restrict__ Wl2, const float* __restrict__ Wr2,
                        unsigned short* Bp) {
    int i = blockIdx.x * 256 + threadIdx.x;
    if (i < NN * 64) {
        float2 v = ((const float2*)x)[i];
        ((unsigned int*)xb)[i] = pack2(v.x, v.y);
    }
    if (i < NN) deg[i] = 0;
    if (i < NG) { gstart[i] = NN; gend[i] = -1; }
    if (i < 3 * 256) bnstats[i] = 0.f;
    if (i < NG * HID) { pool_sum[i] = 0.f; pool_max[i] = 0; }
    if (i < 3 * 32768) {
        int layer = i >> 15;
        int r = i & 32767;
        int nt = r >> 12, kk = (r >> 9) & 7, l = (r >> 3) & 63, j = r & 7;
        int k = kk * 32 + (l >> 4) * 8 + j;
        int n = nt * 16 + (l & 15);
        const float* Wl = layer == 0 ? Wl0 : (layer == 1 ? Wl1 : Wl2);
        const float* Wr = layer == 0 ? Wr0 : (layer == 1 ? Wr1 : Wr2);
        Bp[i] = f2b((k < 128) ? Wl[k * 128 + n] : Wr[(k - 128) * 128 + n]);
    }
}

// bucketized degree histogram: block = (chunk, bucket); atomics stay XCD-local
__global__ void k_hist(const int* __restrict__ dst, int* deg) {
    int bucket = blockIdx.x & (SC_NB - 1);
    int chunk = blockIdx.x / SC_NB;
    int lo = bucket * SC_BSZ, hi = lo + SC_BSZ;
    int base = chunk * SC_CHUNK;
#pragma unroll
    for (int i = 0; i < SC_CHUNK / 256; ++i) {
        int e = base + i * 256 + threadIdx.x;
        if (e < NE) {
            int d = dst[e];
            if (d >= lo && d < hi) atomicAdd(&deg[d], 1);
        }
    }
}

// ---------------- hierarchical exclusive scan of deg (+ graph bounds) ----------------
__global__ void k_scan1(const int* __restrict__ deg, int* blocksum,
                        const int* __restrict__ batch, int* gstart, int* gend) {
    __shared__ int lds[256];
    int t = threadIdx.x, i = blockIdx.x * 256 + t;
    lds[t] = (i < NN) ? deg[i] : 0;
    if (i < NN) {
        int g = batch[i];
        if (i == 0 || batch[i - 1] != g) atomicMin(&gstart[g], i);
        if (i == NN - 1 || batch[i + 1] != g) atomicMax(&gend[g], i);
    }
    __syncthreads();
    for (int off = 128; off > 0; off >>= 1) {
        if (t < off) lds[t] += lds[t + off];
        __syncthreads();
    }
    if (t == 0) blocksum[blockIdx.x] = lds[0];
}

__global__ void k_scan2(const int* __restrict__ blocksum, int* blockoff, int* row_start) {
    __shared__ int lds[256];
    int t = threadIdx.x;
    int v = (t < SCAN_BLOCKS) ? blocksum[t] : 0;
    lds[t] = v;
    __syncthreads();
    for (int off = 1; off < 256; off <<= 1) {
        int u = (t >= off) ? lds[t - off] : 0;
        __syncthreads();
        lds[t] += u;
        __syncthreads();
    }
    if (t < SCAN_BLOCKS) blockoff[t] = lds[t] - v;  // exclusive
    if (t == 255) row_start[NN] = lds[255];         // total == NE
}

__global__ void k_scan3(const int* __restrict__ deg, const int* __restrict__ blockoff,
                        int* row_start, int* cursor) {
    __shared__ int lds[256];
    int t = threadIdx.x, i = blockIdx.x * 256 + t;
    int v = (i < NN) ? deg[i] : 0;
    lds[t] = v;
    __syncthreads();
    for (int off = 1; off < 256; off <<= 1) {
        int u = (t >= off) ? lds[t - off] : 0;
        __syncthreads();
        lds[t] += u;
        __syncthreads();
    }
    if (i < NN) {
        int ex = blockoff[blockIdx.x] + lds[t] - v;
        row_start[i] = ex;
        cursor[i] = ex;
    }
}

// XCD-bucketized scatter (R6): writes for one 400KB col slice stay in one XCD L2
__global__ void k_scatter(const int* __restrict__ src, const int* __restrict__ dst,
                          int* cursor, int* col) {
    int bucket = blockIdx.x & (SC_NB - 1);
    int chunk = blockIdx.x / SC_NB;
    int lo = bucket * SC_BSZ, hi = lo + SC_BSZ;
    int base = chunk * SC_CHUNK;
#pragma unroll
    for (int i = 0; i < SC_CHUNK / 256; ++i) {
        int e = base + i * 256 + threadIdx.x;
        if (e < NE) {
            int d = dst[e];
            if (d >= lo && d < hi) {
                int p = atomicAdd(&cursor[d], 1);
                col[p] = src[e];
            }
        }
    }
}

// ---------------- per-layer kernels ----------------
// mean aggregation over post-norm values computed on the fly; 16 lanes per node,
// 4 nodes per wave. CACHE-BLOCKED (R9): 4 passes over 12.5k-row source slices so
// each XCD's L2 holds the whole slice (3.2MB < 4MB); accumulators live across
// passes. bnstat==nullptr -> raw values (layer 0).
__global__ void k_agg(const unsigned short* __restrict__ h, const int* __restrict__ row_start,
                      const int* __restrict__ col, const float* __restrict__ bnstat,
                      const float* __restrict__ gamma, const float* __restrict__ beta,
                      unsigned short* __restrict__ agg) {
    int wid = threadIdx.x >> 6, lane = threadIdx.x & 63;
    int slot = lane >> 4, sub = lane & 15;
    int node = (blockIdx.x * 4 + wid) * 4 + slot;  // 3125*4*4 == 50000 exactly
    int s = row_start[node], e = row_start[node + 1];
    bool ap = bnstat != nullptr;
    float scv[8], shv[8];
    if (ap) {
#pragma unroll
        for (int i = 0; i < 8; ++i) {
            float2 p = bn_pair(bnstat, gamma, beta, sub * 8 + i);
            scv[i] = p.x; shv[i] = p.y;
        }
    }
    auto tf = [&](float f, int i) -> float {
        return ap ? fmaxf(f * scv[i] + shv[i], 0.f) : f;
    };
    const uint4* h4 = (const uint4*)h;  // one row = 16 uint4 (256B)
    float a0 = 0.f, a1 = 0.f, a2 = 0.f, a3 = 0.f, a4 = 0.f, a5 = 0.f, a6 = 0.f, a7 = 0.f;
    const uint4 z = {0u, 0u, 0u, 0u};
#pragma unroll 1
    for (int pass = 0; pass < AGG_PASSES; ++pass) {
        int ulo = (NN / AGG_PASSES) * pass;
        int uhi = (pass == AGG_PASSES - 1) ? NN : ulo + NN / AGG_PASSES;
        int j = s;
        for (; j + 2 <= e; j += 2) {
            int u0 = col[j], u1 = col[j + 1];
            bool p0 = (u0 >= ulo) & (u0 < uhi);
            bool p1 = (u1 >= ulo) & (u1 < uhi);
            uint4 v0 = p0 ? h4[(size_t)u0 * 16 + sub] : z;
            uint4 v1 = p1 ? h4[(size_t)u1 * 16 + sub] : z;
            if (p0) {
                a0 += tf(blo(v0.x), 0);  a1 += tf(bhi(v0.x), 1);
                a2 += tf(blo(v0.y), 2);  a3 += tf(bhi(v0.y), 3);
                a4 += tf(blo(v0.z), 4);  a5 += tf(bhi(v0.z), 5);
                a6 += tf(blo(v0.w), 6);  a7 += tf(bhi(v0.w), 7);
            }
            if (p1) {
                a0 += tf(blo(v1.x), 0);  a1 += tf(bhi(v1.x), 1);
                a2 += tf(blo(v1.y), 2);  a3 += tf(bhi(v1.y), 3);
                a4 += tf(blo(v1.z), 4);  a5 += tf(bhi(v1.z), 5);
                a6 += tf(blo(v1.w), 6);  a7 += tf(bhi(v1.w), 7);
            }
        }
        if (j < e) {
            int u = col[j];
            if (u >= ulo && u < uhi) {
                uint4 v = h4[(size_t)u * 16 + sub];
                a0 += tf(blo(v.x), 0);  a1 += tf(bhi(v.x), 1);
                a2 += tf(blo(v.y), 2);  a3 += tf(bhi(v.y), 3);
                a4 += tf(blo(v.z), 4);  a5 += tf(bhi(v.z), 5);
                a6 += tf(blo(v.w), 6);  a7 += tf(bhi(v.w), 7);
            }
        }
    }
    float inv = (e > s) ? 1.f / (float)(e - s) : 0.f;
    uint4 o;
    o.x = pack2(a0 * inv, a1 * inv);
    o.y = pack2(a2 * inv, a3 * inv);
    o.z = pack2(a4 * inv, a5 * inv);
    o.w = pack2(a6 * inv, a7 * inv);
    ((uint4*)agg)[(size_t)node * 16 + sub] = o;
}

// apply folded norm (from LDS tables) to a bf16x8 fragment (cols cbase..cbase+7)
__device__ __forceinline__ bf16x8 norm8(bf16x8 v, const float* sc, const float* sh, int cbase) {
    union { bf16x8 v; unsigned short u[8]; } in; in.v = v;
    union { unsigned int u[4]; bf16x8 v; } out;
#pragma unroll
    for (int i = 0; i < 4; ++i) {
        float f0 = fmaxf(b2f(in.u[2 * i]) * sc[cbase + 2 * i] + sh[cbase + 2 * i], 0.f);
        float f1 = fmaxf(b2f(in.u[2 * i + 1]) * sc[cbase + 2 * i + 1] + sh[cbase + 2 * i + 1], 0.f);
        out.u[i] = pack2(f0, f1);
    }
    return out.v;
}

// buf[M,128] <- [buf | norm(h)][M,256] @ Wcat[256,128], bf16 in-place; BN stats of
// THIS layer accumulated; norm params of PREVIOUS layer computed inline into LDS.
__global__ void __launch_bounds__(256) k_gemm(unsigned short* buf,
                                              const unsigned short* h,
                                              const unsigned short* __restrict__ Bp,
                                              const float* __restrict__ pbnstat,
                                              const float* __restrict__ pgamma,
                                              const float* __restrict__ pbeta,
                                              float* bnstat) {
    __shared__ unsigned short Bs[32768];  // 64KB B fragments; reused for stat reduce
    __shared__ float s_sc[128], s_sh[128];
    int t = threadIdx.x;
    {
        const uint4* s4 = (const uint4*)Bp;
        uint4* d4 = (uint4*)Bs;
        for (int i = t; i < 4096; i += 256) d4[i] = s4[i];
    }
    bool ap = pbnstat != nullptr;
    if (ap && t < 128) {
        float2 p = bn_pair(pbnstat, pgamma, pbeta, t);
        s_sc[t] = p.x; s_sh[t] = p.y;
    }
    __syncthreads();
    int wid = t >> 6, lane = t & 63;
    int m = lane & 15, q = lane >> 4;
    int mbase = blockIdx.x * 128 + wid * 32;
    bool active = mbase < NN;
    float s8[8] = {0, 0, 0, 0, 0, 0, 0, 0};
    float ss8[8] = {0, 0, 0, 0, 0, 0, 0, 0};
    if (active) {
        int row0 = mbase + m;
        int row1 = min(mbase + 16 + m, NN - 1);  // clamp tail (stores masked below)
        const bf16x8* Abuf = (const bf16x8*)buf;
        const bf16x8* Ah = (const bf16x8*)h;
        size_t b0 = (size_t)row0 * 16, b1 = (size_t)row1 * 16;
        bf16x8 af0[8], af1[8];
#pragma unroll
        for (int kk = 0; kk < 4; ++kk) {
            af0[kk] = Abuf[b0 + kk * 4 + q];
            af1[kk] = Abuf[b1 + kk * 4 + q];
            bf16x8 h0 = Ah[b0 + kk * 4 + q];
            bf16x8 h1 = Ah[b1 + kk * 4 + q];
            if (ap) {
                int cb = kk * 32 + q * 8;
                h0 = norm8(h0, s_sc, s_sh, cb);
                h1 = norm8(h1, s_sc, s_sh, cb);
            }
            af0[4 + kk] = h0;
            af1[4 + kk] = h1;
        }
        const bf16x8* B = (const bf16x8*)Bs;
        floatx4 acc[2][8];
#pragma unroll
        for (int mt = 0; mt < 2; ++mt)
#pragma unroll
            for (int nt = 0; nt < 8; ++nt) acc[mt][nt] = (floatx4){0.f, 0.f, 0.f, 0.f};
#pragma unroll
        for (int kk = 0; kk < 8; ++kk) {
#pragma unroll
            for (int nt = 0; nt < 8; ++nt) {
                bf16x8 b = B[(nt * 8 + kk) * 64 + lane];
                acc[0][nt] = __builtin_amdgcn_mfma_f32_16x16x32_bf16(af0[kk], b, acc[0][nt], 0, 0, 0);
                acc[1][nt] = __builtin_amdgcn_mfma_f32_16x16x32_bf16(af1[kk], b, acc[1][nt], 0, 0, 0);
            }
        }
#pragma unroll
        for (int mt = 0; mt < 2; ++mt)
#pragma unroll
            for (int nt = 0; nt < 8; ++nt) {
                int c = nt * 16 + m;  // C/D: col = lane&15
#pragma unroll
                for (int reg = 0; reg < 4; ++reg) {
                    int r = mbase + mt * 16 + q * 4 + reg;  // C/D: row = quad*4+reg
                    if (r < NN) {
                        float v = acc[mt][nt][reg];
                        buf[(size_t)r * 128 + c] = f2b(v);
                        s8[nt] += v;
                        ss8[nt] += v * v;
                    }
                }
            }
#pragma unroll
        for (int nt = 0; nt < 8; ++nt) {
            s8[nt] += __shfl_xor(s8[nt], 16, 64);  s8[nt] += __shfl_xor(s8[nt], 32, 64);
            ss8[nt] += __shfl_xor(ss8[nt], 16, 64); ss8[nt] += __shfl_xor(ss8[nt], 32, 64);
        }
    }
    __syncthreads();  // all waves done reading Bs
    float* stf = (float*)Bs;
    if (t < 256) stf[t] = 0.f;
    __syncthreads();
    if (active && lane < 16) {
#pragma unroll
        for (int nt = 0; nt < 8; ++nt) {
            int c = nt * 16 + m;
            atomicAdd(&stf[c], s8[nt]);
            atomicAdd(&stf[128 + c], ss8[nt]);
        }
    }
    __syncthreads();
    if (t < 256) atomicAdd(&bnstat[t], stf[t]);
}

// ---------------- pooling (folded norm inline) + head ----------------
__global__ void k_pool(const unsigned short* __restrict__ h, const int* __restrict__ gstart,
                       const int* __restrict__ gend, const float* __restrict__ bnstat,
                       const float* __restrict__ gamma, const float* __restrict__ beta,
                       float* pool_sum, int* pool_max) {
    int g = blockIdx.x >> 3, chunk = blockIdx.x & 7;
    int s = gstart[g], e = gend[g];
    if (s > e) return;
    int cnt = e - s + 1;
    int per = (cnt + 7) >> 3;
    int r0 = s + chunk * per;
    int r1 = min(r0 + per, e + 1);
    int c = threadIdx.x & 127, half = threadIdx.x >> 7;
    float2 pr = bn_pair(bnstat, gamma, beta, c);
    float sm = 0.f, mx = 0.f;  // post-relu values are >= 0
    for (int r = r0 + half; r < r1; r += 2) {
        float v = fmaxf(b2f(h[(size_t)r * 128 + c]) * pr.x + pr.y, 0.f);
        sm += v;
        mx = fmaxf(mx, v);
    }
    atomicAdd(&pool_sum[g * 128 + c], sm);
    atomicMax(&pool_max[g * 128 + c], __float_as_int(mx));  // valid for >=0 floats
}

__global__ void __launch_bounds__(128) k_head(
    const float* __restrict__ pool_sum, const int* __restrict__ pool_max,
    const int* __restrict__ gstart, const int* __restrict__ gend,
    const float* __restrict__ gfeats,
    const float* __restrict__ W1, const float* __restrict__ bs1,
    const float* __restrict__ W2, const float* __restrict__ bs2,
    const float* __restrict__ W3, const float* __restrict__ bs3,
    float* out) {
    __shared__ float m[288];
    __shared__ float o1[128];
    __shared__ float o2[64];
    int g = blockIdx.x, t = threadIdx.x;
    int s = gstart[g], e = gend[g];
    int cint = e - s + 1;
    float cnt = (float)(cint < 1 ? 1 : cint);
    if (t < 128) {
        m[t] = pool_sum[g * 128 + t] / cnt;
        m[128 + t] = __int_as_float(pool_max[g * 128 + t]);
    }
    if (t < 32) m[256 + t] = gfeats[g * 32 + t];
    __syncthreads();
    float acc = bs1[t];
    for (int k = 0; k < 288; ++k) acc += m[k] * W1[k * 128 + t];
    o1[t] = fmaxf(acc, 0.f);
    __syncthreads();
    if (t < 64) {
        float a2 = bs2[t];
        for (int k = 0; k < 128; ++k) a2 += o1[k] * W2[k * 64 + t];
        o2[t] = fmaxf(a2, 0.f);
    }
    __syncthreads();
    if (t < 64) {
        float p = o2[t] * W3[t];
#pragma unroll
        for (int off = 32; off; off >>= 1) p += __shfl_down(p, off, 64);
        if (t == 0) out[g] = p + bs3[0];
    }
}

// ---------------- launch ----------------
extern "C" void kernel_launch(void* const* d_in, const int* in_sizes, int n_in,
                              void* d_out, int out_size, void* d_ws, size_t ws_size,
                              hipStream_t stream) {
    const float* x = (const float*)d_in[0];
    const int* ei = (const int*)d_in[1];
    const int* batch = (const int*)d_in[2];
    const float* gfeats = (const float*)d_in[3];
    const float *Wl[3], *Wr[3], *gma[3], *bta[3];
    for (int i = 0; i < 3; ++i) {
        Wl[i] = (const float*)d_in[4 + 5 * i];
        // d_in[5+5i] = bl (cancelled by BatchNorm; unused)
        Wr[i] = (const float*)d_in[6 + 5 * i];
        gma[i] = (const float*)d_in[7 + 5 * i];
        bta[i] = (const float*)d_in[8 + 5 * i];
    }
    const float* W1 = (const float*)d_in[19];
    const float* bs1 = (const float*)d_in[20];
    const float* W2 = (const float*)d_in[21];
    const float* bs2 = (const float*)d_in[22];
    const float* W3 = (const float*)d_in[23];
    const float* bs3 = (const float*)d_in[24];

    char* p = (char*)d_ws;
    auto alloc = [&](size_t bytes) -> char* {
        char* r = p;
        p += (bytes + 255) & ~(size_t)255;
        return r;
    };
    int* deg = (int*)alloc(NN * 4);
    int* row_start = (int*)alloc((NN + 1) * 4);
    int* cursor = (int*)alloc(NN * 4);
    int* col = (int*)alloc(NE * 4);
    int* gstart = (int*)alloc(NG * 4);
    int* gend = (int*)alloc(NG * 4);
    float* bnstats = (float*)alloc(3 * 256 * 4);
    float* pool_sum = (float*)alloc(NG * HID * 4);
    int* pool_max = (int*)alloc(NG * HID * 4);
    int* blocksum = (int*)alloc(SCAN_BLOCKS * 4);
    int* blockoff = (int*)alloc(SCAN_BLOCKS * 4);
    unsigned short* Bp = (unsigned short*)alloc(3 * 32768 * 2);
    unsigned short* xb = (unsigned short*)alloc((size_t)NN * 128 * 2);
    unsigned short* b0 = (unsigned short*)alloc((size_t)NN * 128 * 2);
    unsigned short* b1 = (unsigned short*)alloc((size_t)NN * 128 * 2);

    const int* srcv = ei;
    const int* dstv = ei + NE;

    k_setup<<<(NN * 64 + 255) / 256, 256, 0, stream>>>(
        x, xb, deg, gstart, gend, bnstats, pool_sum, pool_max,
        Wl[0], Wr[0], Wl[1], Wr[1], Wl[2], Wr[2], Bp);
    k_hist<<<SC_CHUNKS * SC_NB, 256, 0, stream>>>(dstv, deg);
    k_scan1<<<SCAN_BLOCKS, 256, 0, stream>>>(deg, blocksum, batch, gstart, gend);
    k_scan2<<<1, 256, 0, stream>>>(blocksum, blockoff, row_start);
    k_scan3<<<SCAN_BLOCKS, 256, 0, stream>>>(deg, blockoff, row_start, cursor);
    k_scatter<<<SC_CHUNKS * SC_NB, 256, 0, stream>>>(srcv, dstv, cursor, col);

    // layer chain: hin (pre-BN of prev layer, or xb) -> w (pre-BN of this layer)
    const unsigned short* hin = xb;
    unsigned short* work[3] = {b0, b1, b0};
    for (int l = 0; l < 3; ++l) {
        unsigned short* w = work[l];
        const float* pb = (l == 0) ? nullptr : bnstats + (l - 1) * 256;
        const float* pg = (l == 0) ? nullptr : gma[l - 1];
        const float* pt = (l == 0) ? nullptr : bta[l - 1];
        k_agg<<<(NN + 15) / 16, 256, 0, stream>>>(hin, row_start, col, pb, pg, pt, w);
        k_gemm<<<GEMM_BLOCKS, 256, 0, stream>>>(w, hin, Bp + l * 32768, pb, pg, pt,
                                                bnstats + l * 256);
        hin = w;
    }
    k_pool<<<NG * 8, 256, 0, stream>>>(hin, gstart, gend, bnstats + 2 * 256, gma[2], bta[2],
                                       pool_sum, pool_max);
    k_head<<<NG, 128, 0, stream>>>(pool_sum, pool_max, gstart, gend, gfeats,
                                   W1, bs1, W2, bs2, W3, bs3, (float*)d_out);
}

// Round 11
// 399.481 us; speedup vs baseline: 1.4776x; 1.4776x over previous
//
#include <hip/hip_runtime.h>
#include <stdint.h>

#define NN 50000
#define NE 800000
#define HID 128
#define NG 64
#define BN_EPS 1e-5f
#define SCAN_BLOCKS 196  // 196*256 = 50176 >= NN
#define GEMM_BLOCKS ((NN + 127) / 128)
#define SC_NB 8                                  // buckets (== XCD count)
#define SC_BSZ ((NN + SC_NB - 1) / SC_NB)        // 6250 nodes per bucket
#define SC_CHUNK 4096                            // edges per block
#define SC_CHUNKS ((NE + SC_CHUNK - 1) / SC_CHUNK)

typedef __bf16 bf16x8 __attribute__((ext_vector_type(8)));
typedef float floatx4 __attribute__((ext_vector_type(4)));

__device__ __forceinline__ float b2f(unsigned short u) {
    union { unsigned int i; float f; } x; x.i = ((unsigned int)u) << 16; return x.f;
}
__device__ __forceinline__ float blo(unsigned int d) { return __uint_as_float(d << 16); }
__device__ __forceinline__ float bhi(unsigned int d) { return __uint_as_float(d & 0xffff0000u); }
__device__ __forceinline__ unsigned short f2b(float f) {
    union { float f; unsigned int i; } x; x.f = f; unsigned int i = x.i;
    if ((i & 0x7f800000u) == 0x7f800000u) return (unsigned short)(i >> 16); // inf/nan
    return (unsigned short)((i + 0x7fffu + ((i >> 16) & 1u)) >> 16);        // RNE
}
__device__ __forceinline__ unsigned int pack2(float f0, float f1) {
    return (((unsigned int)f2b(f1)) << 16) | f2b(f0);
}
// folded BN scale/shift for column c (from raw sums)
__device__ __forceinline__ float2 bn_pair(const float* __restrict__ bnstat,
                                          const float* __restrict__ gamma,
                                          const float* __restrict__ beta, int c) {
    float mu = bnstat[c] * (1.f / NN);
    float var = bnstat[128 + c] * (1.f / NN) - mu * mu;
    float s = gamma[c] * rsqrtf(var + BN_EPS);
    return make_float2(s, beta[c] - mu * s);
}

// ---------------- setup (incl. weight prep) ----------------
// Pre-transpose fp32 [Wl;Wr] (256x128) into bf16 MFMA B-fragment order:
// Bp[layer][nt][kk][lane][j] = Wcat[kk*32+(lane>>4)*8+j][nt*16+(lane&15)]
__global__ void k_setup(const float* __restrict__ x, unsigned short* xb, int* deg,
                        int* gstart, int* gend, float* bnstats,
                        float* pool_sum, int* pool_max,
                        const float* __restrict__ Wl0, const float* __restrict__ Wr0,
                        const float* __restrict__ Wl1, const float* __restrict__ Wr1,
                        const float* __restrict__ Wl2, const float* __restrict__ Wr2,
                        unsigned short* Bp) {
    int i = blockIdx.x * 256 + threadIdx.x;
    if (i < NN * 64) {
        float2 v = ((const float2*)x)[i];
        ((unsigned int*)xb)[i] = pack2(v.x, v.y);
    }
    if (i < NN) deg[i] = 0;
    if (i < NG) { gstart[i] = NN; gend[i] = -1; }
    if (i < 3 * 256) bnstats[i] = 0.f;
    if (i < NG * HID) { pool_sum[i] = 0.f; pool_max[i] = 0; }
    if (i < 3 * 32768) {
        int layer = i >> 15;
        int r = i & 32767;
        int nt = r >> 12, kk = (r >> 9) & 7, l = (r >> 3) & 63, j = r & 7;
        int k = kk * 32 + (l >> 4) * 8 + j;
        int n = nt * 16 + (l & 15);
        const float* Wl = layer == 0 ? Wl0 : (layer == 1 ? Wl1 : Wl2);
        const float* Wr = layer == 0 ? Wr0 : (layer == 1 ? Wr1 : Wr2);
        Bp[i] = f2b((k < 128) ? Wl[k * 128 + n] : Wr[(k - 128) * 128 + n]);
    }
}

// bucketized degree histogram: block = (chunk, bucket); atomics stay XCD-local
__global__ void k_hist(const int* __restrict__ dst, int* deg) {
    int bucket = blockIdx.x & (SC_NB - 1);
    int chunk = blockIdx.x / SC_NB;
    int lo = bucket * SC_BSZ, hi = lo + SC_BSZ;
    int base = chunk * SC_CHUNK;
#pragma unroll
    for (int i = 0; i < SC_CHUNK / 256; ++i) {
        int e = base + i * 256 + threadIdx.x;
        if (e < NE) {
            int d = dst[e];
            if (d >= lo && d < hi) atomicAdd(&deg[d], 1);
        }
    }
}

// ---------------- hierarchical exclusive scan of deg (+ graph bounds) ----------------
__global__ void k_scan1(const int* __restrict__ deg, int* blocksum,
                        const int* __restrict__ batch, int* gstart, int* gend) {
    __shared__ int lds[256];
    int t = threadIdx.x, i = blockIdx.x * 256 + t;
    lds[t] = (i < NN) ? deg[i] : 0;
    if (i < NN) {
        int g = batch[i];
        if (i == 0 || batch[i - 1] != g) atomicMin(&gstart[g], i);
        if (i == NN - 1 || batch[i + 1] != g) atomicMax(&gend[g], i);
    }
    __syncthreads();
    for (int off = 128; off > 0; off >>= 1) {
        if (t < off) lds[t] += lds[t + off];
        __syncthreads();
    }
    if (t == 0) blocksum[blockIdx.x] = lds[0];
}

__global__ void k_scan2(const int* __restrict__ blocksum, int* blockoff, int* row_start) {
    __shared__ int lds[256];
    int t = threadIdx.x;
    int v = (t < SCAN_BLOCKS) ? blocksum[t] : 0;
    lds[t] = v;
    __syncthreads();
    for (int off = 1; off < 256; off <<= 1) {
        int u = (t >= off) ? lds[t - off] : 0;
        __syncthreads();
        lds[t] += u;
        __syncthreads();
    }
    if (t < SCAN_BLOCKS) blockoff[t] = lds[t] - v;  // exclusive
    if (t == 255) row_start[NN] = lds[255];         // total == NE
}

__global__ void k_scan3(const int* __restrict__ deg, const int* __restrict__ blockoff,
                        int* row_start, int* cursor) {
    __shared__ int lds[256];
    int t = threadIdx.x, i = blockIdx.x * 256 + t;
    int v = (i < NN) ? deg[i] : 0;
    lds[t] = v;
    __syncthreads();
    for (int off = 1; off < 256; off <<= 1) {
        int u = (t >= off) ? lds[t - off] : 0;
        __syncthreads();
        lds[t] += u;
        __syncthreads();
    }
    if (i < NN) {
        int ex = blockoff[blockIdx.x] + lds[t] - v;
        row_start[i] = ex;
        cursor[i] = ex;
    }
}

// XCD-bucketized scatter (R6): writes for one 400KB col slice stay in one XCD L2
__global__ void k_scatter(const int* __restrict__ src, const int* __restrict__ dst,
                          int* cursor, int* col) {
    int bucket = blockIdx.x & (SC_NB - 1);
    int chunk = blockIdx.x / SC_NB;
    int lo = bucket * SC_BSZ, hi = lo + SC_BSZ;
    int base = chunk * SC_CHUNK;
#pragma unroll
    for (int i = 0; i < SC_CHUNK / 256; ++i) {
        int e = base + i * 256 + threadIdx.x;
        if (e < NE) {
            int d = dst[e];
            if (d >= lo && d < hi) {
                int p = atomicAdd(&cursor[d], 1);
                col[p] = src[e];
            }
        }
    }
}

// ---------------- per-layer kernels ----------------
// mean aggregation over post-norm values computed on the fly; 16 lanes per node
// (sub = 16B chunk of the 256B row), 4 nodes per wave; single pass (R10's
// per-wave "cache-blocking" regressed: no cross-block time coordination).
// Gather unrolled x4 for 4 independent row-reads in flight per lane.
__global__ void k_agg(const unsigned short* __restrict__ h, const int* __restrict__ row_start,
                      const int* __restrict__ col, const float* __restrict__ bnstat,
                      const float* __restrict__ gamma, const float* __restrict__ beta,
                      unsigned short* __restrict__ agg) {
    int wid = threadIdx.x >> 6, lane = threadIdx.x & 63;
    int slot = lane >> 4, sub = lane & 15;
    int node = (blockIdx.x * 4 + wid) * 4 + slot;  // 3125*4*4 == 50000 exactly
    int s = row_start[node], e = row_start[node + 1];
    bool ap = bnstat != nullptr;
    float scv[8], shv[8];
    if (ap) {
#pragma unroll
        for (int i = 0; i < 8; ++i) {
            float2 p = bn_pair(bnstat, gamma, beta, sub * 8 + i);
            scv[i] = p.x; shv[i] = p.y;
        }
    }
    auto tf = [&](float f, int i) -> float {
        return ap ? fmaxf(f * scv[i] + shv[i], 0.f) : f;
    };
    const uint4* h4 = (const uint4*)h;  // one row = 16 uint4 (256B)
    float a0 = 0.f, a1 = 0.f, a2 = 0.f, a3 = 0.f, a4 = 0.f, a5 = 0.f, a6 = 0.f, a7 = 0.f;
    int j = s;
    for (; j + 4 <= e; j += 4) {
        int u0 = col[j], u1 = col[j + 1], u2 = col[j + 2], u3 = col[j + 3];
        uint4 v0 = h4[(size_t)u0 * 16 + sub];
        uint4 v1 = h4[(size_t)u1 * 16 + sub];
        uint4 v2 = h4[(size_t)u2 * 16 + sub];
        uint4 v3 = h4[(size_t)u3 * 16 + sub];
        a0 += (tf(blo(v0.x), 0) + tf(blo(v1.x), 0)) + (tf(blo(v2.x), 0) + tf(blo(v3.x), 0));
        a1 += (tf(bhi(v0.x), 1) + tf(bhi(v1.x), 1)) + (tf(bhi(v2.x), 1) + tf(bhi(v3.x), 1));
        a2 += (tf(blo(v0.y), 2) + tf(blo(v1.y), 2)) + (tf(blo(v2.y), 2) + tf(blo(v3.y), 2));
        a3 += (tf(bhi(v0.y), 3) + tf(bhi(v1.y), 3)) + (tf(bhi(v2.y), 3) + tf(bhi(v3.y), 3));
        a4 += (tf(blo(v0.z), 4) + tf(blo(v1.z), 4)) + (tf(blo(v2.z), 4) + tf(blo(v3.z), 4));
        a5 += (tf(bhi(v0.z), 5) + tf(bhi(v1.z), 5)) + (tf(bhi(v2.z), 5) + tf(bhi(v3.z), 5));
        a6 += (tf(blo(v0.w), 6) + tf(blo(v1.w), 6)) + (tf(blo(v2.w), 6) + tf(blo(v3.w), 6));
        a7 += (tf(bhi(v0.w), 7) + tf(bhi(v1.w), 7)) + (tf(bhi(v2.w), 7) + tf(bhi(v3.w), 7));
    }
    for (; j < e; ++j) {
        int u = col[j];
        uint4 v = h4[(size_t)u * 16 + sub];
        a0 += tf(blo(v.x), 0);  a1 += tf(bhi(v.x), 1);
        a2 += tf(blo(v.y), 2);  a3 += tf(bhi(v.y), 3);
        a4 += tf(blo(v.z), 4);  a5 += tf(bhi(v.z), 5);
        a6 += tf(blo(v.w), 6);  a7 += tf(bhi(v.w), 7);
    }
    float inv = (e > s) ? 1.f / (float)(e - s) : 0.f;
    uint4 o;
    o.x = pack2(a0 * inv, a1 * inv);
    o.y = pack2(a2 * inv, a3 * inv);
    o.z = pack2(a4 * inv, a5 * inv);
    o.w = pack2(a6 * inv, a7 * inv);
    ((uint4*)agg)[(size_t)node * 16 + sub] = o;
}

// apply folded norm (from LDS tables) to a bf16x8 fragment (cols cbase..cbase+7)
__device__ __forceinline__ bf16x8 norm8(bf16x8 v, const float* sc, const float* sh, int cbase) {
    union { bf16x8 v; unsigned short u[8]; } in; in.v = v;
    union { unsigned int u[4]; bf16x8 v; } out;
#pragma unroll
    for (int i = 0; i < 4; ++i) {
        float f0 = fmaxf(b2f(in.u[2 * i]) * sc[cbase + 2 * i] + sh[cbase + 2 * i], 0.f);
        float f1 = fmaxf(b2f(in.u[2 * i + 1]) * sc[cbase + 2 * i + 1] + sh[cbase + 2 * i + 1], 0.f);
        out.u[i] = pack2(f0, f1);
    }
    return out.v;
}

// buf[M,128] <- [buf | norm(h)][M,256] @ Wcat[256,128], bf16 in-place; BN stats of
// THIS layer accumulated; norm params of PREVIOUS layer computed inline into LDS.
__global__ void __launch_bounds__(256) k_gemm(unsigned short* buf,
                                              const unsigned short* h,
                                              const unsigned short* __restrict__ Bp,
                                              const float* __restrict__ pbnstat,
                                              const float* __restrict__ pgamma,
                                              const float* __restrict__ pbeta,
                                              float* bnstat) {
    __shared__ unsigned short Bs[32768];  // 64KB B fragments; reused for stat reduce
    __shared__ float s_sc[128], s_sh[128];
    int t = threadIdx.x;
    {
        const uint4* s4 = (const uint4*)Bp;
        uint4* d4 = (uint4*)Bs;
        for (int i = t; i < 4096; i += 256) d4[i] = s4[i];
    }
    bool ap = pbnstat != nullptr;
    if (ap && t < 128) {
        float2 p = bn_pair(pbnstat, pgamma, pbeta, t);
        s_sc[t] = p.x; s_sh[t] = p.y;
    }
    __syncthreads();
    int wid = t >> 6, lane = t & 63;
    int m = lane & 15, q = lane >> 4;
    int mbase = blockIdx.x * 128 + wid * 32;
    bool active = mbase < NN;
    float s8[8] = {0, 0, 0, 0, 0, 0, 0, 0};
    float ss8[8] = {0, 0, 0, 0, 0, 0, 0, 0};
    if (active) {
        int row0 = mbase + m;
        int row1 = min(mbase + 16 + m, NN - 1);  // clamp tail (stores masked below)
        const bf16x8* Abuf = (const bf16x8*)buf;
        const bf16x8* Ah = (const bf16x8*)h;
        size_t b0 = (size_t)row0 * 16, b1 = (size_t)row1 * 16;
        bf16x8 af0[8], af1[8];
#pragma unroll
        for (int kk = 0; kk < 4; ++kk) {
            af0[kk] = Abuf[b0 + kk * 4 + q];
            af1[kk] = Abuf[b1 + kk * 4 + q];
            bf16x8 h0 = Ah[b0 + kk * 4 + q];
            bf16x8 h1 = Ah[b1 + kk * 4 + q];
            if (ap) {
                int cb = kk * 32 + q * 8;
                h0 = norm8(h0, s_sc, s_sh, cb);
                h1 = norm8(h1, s_sc, s_sh, cb);
            }
            af0[4 + kk] = h0;
            af1[4 + kk] = h1;
        }
        const bf16x8* B = (const bf16x8*)Bs;
        floatx4 acc[2][8];
#pragma unroll
        for (int mt = 0; mt < 2; ++mt)
#pragma unroll
            for (int nt = 0; nt < 8; ++nt) acc[mt][nt] = (floatx4){0.f, 0.f, 0.f, 0.f};
#pragma unroll
        for (int kk = 0; kk < 8; ++kk) {
#pragma unroll
            for (int nt = 0; nt < 8; ++nt) {
                bf16x8 b = B[(nt * 8 + kk) * 64 + lane];
                acc[0][nt] = __builtin_amdgcn_mfma_f32_16x16x32_bf16(af0[kk], b, acc[0][nt], 0, 0, 0);
                acc[1][nt] = __builtin_amdgcn_mfma_f32_16x16x32_bf16(af1[kk], b, acc[1][nt], 0, 0, 0);
            }
        }
#pragma unroll
        for (int mt = 0; mt < 2; ++mt)
#pragma unroll
            for (int nt = 0; nt < 8; ++nt) {
                int c = nt * 16 + m;  // C/D: col = lane&15
#pragma unroll
                for (int reg = 0; reg < 4; ++reg) {
                    int r = mbase + mt * 16 + q * 4 + reg;  // C/D: row = quad*4+reg
                    if (r < NN) {
                        float v = acc[mt][nt][reg];
                        buf[(size_t)r * 128 + c] = f2b(v);
                        s8[nt] += v;
                        ss8[nt] += v * v;
                    }
                }
            }
#pragma unroll
        for (int nt = 0; nt < 8; ++nt) {
            s8[nt] += __shfl_xor(s8[nt], 16, 64);  s8[nt] += __shfl_xor(s8[nt], 32, 64);
            ss8[nt] += __shfl_xor(ss8[nt], 16, 64); ss8[nt] += __shfl_xor(ss8[nt], 32, 64);
        }
    }
    __syncthreads();  // all waves done reading Bs
    float* stf = (float*)Bs;
    if (t < 256) stf[t] = 0.f;
    __syncthreads();
    if (active && lane < 16) {
#pragma unroll
        for (int nt = 0; nt < 8; ++nt) {
            int c = nt * 16 + m;
            atomicAdd(&stf[c], s8[nt]);
            atomicAdd(&stf[128 + c], ss8[nt]);
        }
    }
    __syncthreads();
    if (t < 256) atomicAdd(&bnstat[t], stf[t]);
}

// ---------------- pooling (folded norm inline) + head ----------------
__global__ void k_pool(const unsigned short* __restrict__ h, const int* __restrict__ gstart,
                       const int* __restrict__ gend, const float* __restrict__ bnstat,
                       const float* __restrict__ gamma, const float* __restrict__ beta,
                       float* pool_sum, int* pool_max) {
    int g = blockIdx.x >> 3, chunk = blockIdx.x & 7;
    int s = gstart[g], e = gend[g];
    if (s > e) return;
    int cnt = e - s + 1;
    int per = (cnt + 7) >> 3;
    int r0 = s + chunk * per;
    int r1 = min(r0 + per, e + 1);
    int c = threadIdx.x & 127, half = threadIdx.x >> 7;
    float2 pr = bn_pair(bnstat, gamma, beta, c);
    float sm = 0.f, mx = 0.f;  // post-relu values are >= 0
    for (int r = r0 + half; r < r1; r += 2) {
        float v = fmaxf(b2f(h[(size_t)r * 128 + c]) * pr.x + pr.y, 0.f);
        sm += v;
        mx = fmaxf(mx, v);
    }
    atomicAdd(&pool_sum[g * 128 + c], sm);
    atomicMax(&pool_max[g * 128 + c], __float_as_int(mx));  // valid for >=0 floats
}

__global__ void __launch_bounds__(128) k_head(
    const float* __restrict__ pool_sum, const int* __restrict__ pool_max,
    const int* __restrict__ gstart, const int* __restrict__ gend,
    const float* __restrict__ gfeats,
    const float* __restrict__ W1, const float* __restrict__ bs1,
    const float* __restrict__ W2, const float* __restrict__ bs2,
    const float* __restrict__ W3, const float* __restrict__ bs3,
    float* out) {
    __shared__ float m[288];
    __shared__ float o1[128];
    __shared__ float o2[64];
    int g = blockIdx.x, t = threadIdx.x;
    int s = gstart[g], e = gend[g];
    int cint = e - s + 1;
    float cnt = (float)(cint < 1 ? 1 : cint);
    if (t < 128) {
        m[t] = pool_sum[g * 128 + t] / cnt;
        m[128 + t] = __int_as_float(pool_max[g * 128 + t]);
    }
    if (t < 32) m[256 + t] = gfeats[g * 32 + t];
    __syncthreads();
    float acc = bs1[t];
    for (int k = 0; k < 288; ++k) acc += m[k] * W1[k * 128 + t];
    o1[t] = fmaxf(acc, 0.f);
    __syncthreads();
    if (t < 64) {
        float a2 = bs2[t];
        for (int k = 0; k < 128; ++k) a2 += o1[k] * W2[k * 64 + t];
        o2[t] = fmaxf(a2, 0.f);
    }
    __syncthreads();
    if (t < 64) {
        float p = o2[t] * W3[t];
#pragma unroll
        for (int off = 32; off; off >>= 1) p += __shfl_down(p, off, 64);
        if (t == 0) out[g] = p + bs3[0];
    }
}

// ---------------- launch ----------------
extern "C" void kernel_launch(void* const* d_in, const int* in_sizes, int n_in,
                              void* d_out, int out_size, void* d_ws, size_t ws_size,
                              hipStream_t stream) {
    const float* x = (const float*)d_in[0];
    const int* ei = (const int*)d_in[1];
    const int* batch = (const int*)d_in[2];
    const float* gfeats = (const float*)d_in[3];
    const float *Wl[3], *Wr[3], *gma[3], *bta[3];
    for (int i = 0; i < 3; ++i) {
        Wl[i] = (const float*)d_in[4 + 5 * i];
        // d_in[5+5i] = bl (cancelled by BatchNorm; unused)
        Wr[i] = (const float*)d_in[6 + 5 * i];
        gma[i] = (const float*)d_in[7 + 5 * i];
        bta[i] = (const float*)d_in[8 + 5 * i];
    }
    const float* W1 = (const float*)d_in[19];
    const float* bs1 = (const float*)d_in[20];
    const float* W2 = (const float*)d_in[21];
    const float* bs2 = (const float*)d_in[22];
    const float* W3 = (const float*)d_in[23];
    const float* bs3 = (const float*)d_in[24];

    char* p = (char*)d_ws;
    auto alloc = [&](size_t bytes) -> char* {
        char* r = p;
        p += (bytes + 255) & ~(size_t)255;
        return r;
    };
    int* deg = (int*)alloc(NN * 4);
    int* row_start = (int*)alloc((NN + 1) * 4);
    int* cursor = (int*)alloc(NN * 4);
    int* col = (int*)alloc(NE * 4);
    int* gstart = (int*)alloc(NG * 4);
    int* gend = (int*)alloc(NG * 4);
    float* bnstats = (float*)alloc(3 * 256 * 4);
    float* pool_sum = (float*)alloc(NG * HID * 4);
    int* pool_max = (int*)alloc(NG * HID * 4);
    int* blocksum = (int*)alloc(SCAN_BLOCKS * 4);
    int* blockoff = (int*)alloc(SCAN_BLOCKS * 4);
    unsigned short* Bp = (unsigned short*)alloc(3 * 32768 * 2);
    unsigned short* xb = (unsigned short*)alloc((size_t)NN * 128 * 2);
    unsigned short* b0 = (unsigned short*)alloc((size_t)NN * 128 * 2);
    unsigned short* b1 = (unsigned short*)alloc((size_t)NN * 128 * 2);

    const int* srcv = ei;
    const int* dstv = ei + NE;

    k_setup<<<(NN * 64 + 255) / 256, 256, 0, stream>>>(
        x, xb, deg, gstart, gend, bnstats, pool_sum, pool_max,
        Wl[0], Wr[0], Wl[1], Wr[1], Wl[2], Wr[2], Bp);
    k_hist<<<SC_CHUNKS * SC_NB, 256, 0, stream>>>(dstv, deg);
    k_scan1<<<SCAN_BLOCKS, 256, 0, stream>>>(deg, blocksum, batch, gstart, gend);
    k_scan2<<<1, 256, 0, stream>>>(blocksum, blockoff, row_start);
    k_scan3<<<SCAN_BLOCKS, 256, 0, stream>>>(deg, blockoff, row_start, cursor);
    k_scatter<<<SC_CHUNKS * SC_NB, 256, 0, stream>>>(srcv, dstv, cursor, col);

    // layer chain: hin (pre-BN of prev layer, or xb) -> w (pre-BN of this layer)
    const unsigned short* hin = xb;
    unsigned short* work[3] = {b0, b1, b0};
    for (int l = 0; l < 3; ++l) {
        unsigned short* w = work[l];
        const float* pb = (l == 0) ? nullptr : bnstats + (l - 1) * 256;
        const float* pg = (l == 0) ? nullptr : gma[l - 1];
        const float* pt = (l == 0) ? nullptr : bta[l - 1];
        k_agg<<<(NN + 15) / 16, 256, 0, stream>>>(hin, row_start, col, pb, pg, pt, w);
        k_gemm<<<GEMM_BLOCKS, 256, 0, stream>>>(w, hin, Bp + l * 32768, pb, pg, pt,
                                                bnstats + l * 256);
        hin = w;
    }
    k_pool<<<NG * 8, 256, 0, stream>>>(hin, gstart, gend, bnstats + 2 * 256, gma[2], bta[2],
                                       pool_sum, pool_max);
    k_head<<<NG, 128, 0, stream>>>(pool_sum, pool_max, gstart, gend, gfeats,
                                   W1, bs1, W2, bs2, W3, bs3, (float*)d_out);
}